// Round 8
// baseline (413.030 us; speedup 1.0000x reference)
//
#include <hip/hip_runtime.h>
#include <stdint.h>

// ---------------------------------------------------------------------------
// FeatureMapTransformer: dual cross-attention (rd / dr paths), B=2, C=512,
// H=W=64 -> N=M=4096.
//   Qt[n][c], Kt[m][c] (transposed conv outs), V[c][m]        (bf16)
//   Et[n][m] = bf16(exp(sum_c Kt[m][c] Qt[n][c]))             (k_qk)
//   partial S[m] = sum_n exp(T) fused into k_qk -> c[m] = 1/S (k_stats2)
//   V'[c][m] = V[c][m] * c[m]                                 (k_vscale)
//   O[c][n]  = sum_m V'[c][m] E[n][m]                         (k_pv, SPLIT-K)
//   out = relu(gamma*(p0+p1) + resid)                          (k_red)
// Staging: global_load_lds width-16 async DMA, NSUB 32-k sub-tiles per
// barrier pair. XOR chunk swizzle on the GLOBAL address side -> fragment
// ds_read_b128 stays at free 2-way aliasing (0 conflicts, round-5/7 verified).
// Round-8: k_pv split-K (kc=2, K=2048 each, NSUB=2/32KB LDS). Rationale:
// round-7 k_pv grid 512 = 2 blocks/CU AND 64KB LDS = 2/CU -> 25% occupancy,
// >50% stall (MfmaUtil 26 + VALU 19 + HBM 22, nothing saturated). Split-K
// doubles co-resident blocks to 4/CU without shrinking the 128x128 tile.
// f32 partials: kc=0 -> d_out (final layout), kc=1 -> dead Q/K qkv slots
// (0-3, 6-9; V' lives in 4,5,10,11). k_red fuses add+gamma+resid+relu.
// ---------------------------------------------------------------------------

typedef __attribute__((ext_vector_type(8))) __bf16 bf16x8;
typedef __attribute__((ext_vector_type(4))) float f32x4;

__device__ __forceinline__ unsigned short f2bf(float f) {
  union { float f; unsigned u; } v; v.f = f;
  unsigned r = v.u + 0x7FFFu + ((v.u >> 16) & 1u);
  return (unsigned short)(r >> 16);
}
__device__ __forceinline__ float bf2f(unsigned short b) {
  union { unsigned u; float f; } v; v.u = ((unsigned)b) << 16;
  return v.f;
}

__device__ __forceinline__ void async_copy16(const unsigned short* g,
                                             unsigned short* l) {
  __builtin_amdgcn_global_load_lds(
      (const __attribute__((address_space(1))) unsigned int*)g,
      (__attribute__((address_space(3))) unsigned int*)l, 16, 0, 0);
}

// C[128x128 at (rowbase,colbase)] += A[row][k] * B[col][k]^T, K-contig A/B.
// Al/Bl: NSUB sub-tiles of 128x32 (4096 shorts each). 16B chunk c of row r
// lives at slot c^((r>>1)&3).
template <int NSUB>
__device__ __forceinline__ void gemm_core(
    const unsigned short* __restrict__ Ag, const unsigned short* __restrict__ Bg,
    int K, int lda, int ldb, int rowbase, int colbase,
    f32x4 (&acc)[4][4], unsigned short* Al, unsigned short* Bl) {
  const int tid = threadIdx.x;
  const int w = tid >> 6, lane = tid & 63;
  const int quad = lane >> 4, l16 = lane & 15;
  const int wm = (w >> 1) << 6, wn = (w & 1) << 6;
  const int rbase = (w << 5) + (lane >> 2);

  for (int k0 = 0; k0 < K; k0 += 32 * NSUB) {
#pragma unroll
    for (int half = 0; half < NSUB; ++half) {
      int kh = k0 + (half << 5);
      unsigned short* Ah = Al + (half << 12);
      unsigned short* Bh = Bl + (half << 12);
#pragma unroll
      for (int i = 0; i < 2; ++i) {
        int rloc = rbase + (i << 4);
        int cg = (lane & 3) ^ ((rloc >> 1) & 3);
        int koff = kh + (cg << 3);
        int ldsoff = ((w << 5) + (i << 4)) << 5;
        async_copy16(Ag + (size_t)(rowbase + rloc) * lda + koff, Ah + ldsoff);
        async_copy16(Bg + (size_t)(colbase + rloc) * ldb + koff, Bh + ldsoff);
      }
    }
    __syncthreads();
#pragma unroll
    for (int half = 0; half < NSUB; ++half) {
      unsigned short* Ah = Al + (half << 12);
      unsigned short* Bh = Bl + (half << 12);
      bf16x8 af[4], bfr[4];
#pragma unroll
      for (int i = 0; i < 4; ++i) {
        int r = wm + (i << 4) + l16;
        af[i] = *(const bf16x8*)(Ah + (r << 5) + ((quad ^ ((r >> 1) & 3)) << 3));
      }
#pragma unroll
      for (int j = 0; j < 4; ++j) {
        int r = wn + (j << 4) + l16;
        bfr[j] = *(const bf16x8*)(Bh + (r << 5) + ((quad ^ ((r >> 1) & 3)) << 3));
      }
#pragma unroll
      for (int i = 0; i < 4; ++i)
#pragma unroll
        for (int j = 0; j < 4; ++j)
          acc[i][j] = __builtin_amdgcn_mfma_f32_16x16x32_bf16(af[i], bfr[j], acc[i][j], 0, 0, 0);
    }
    __syncthreads();
  }
}

// ---------------- weight fp32 -> bf16 -----------------------------------
struct WArgs { const float* src[6]; unsigned short* dst[6]; };
__global__ __launch_bounds__(256) void k_cvtw(WArgs a) {
  int z = blockIdx.y;
  int i = blockIdx.x * 256 + threadIdx.x;
  a.dst[z][i] = f2bf(a.src[z][i]);
}

// ---------------- transpose+convert: x[b][c][n] f32 -> Xt[b][n][c] bf16 --
struct TArgs { const float* src[4]; unsigned short* dst[4]; };
__global__ __launch_bounds__(256) void k_tcvt(TArgs a) {
  __shared__ float tile[32][33];
  const float* src = a.src[blockIdx.z];
  unsigned short* dst = a.dst[blockIdx.z];
  int n0 = blockIdx.x << 5;
  int r0 = blockIdx.y << 5;
  int tx = threadIdx.x & 31, ty = threadIdx.x >> 5;
#pragma unroll
  for (int i = 0; i < 4; ++i)
    tile[ty * 4 + i][tx] = src[(size_t)(r0 + ty * 4 + i) * 4096 + n0 + tx];
  __syncthreads();
  int b = r0 >> 9, c0 = r0 & 511;
#pragma unroll
  for (int i = 0; i < 4; ++i) {
    int nn = ty * 4 + i;
    dst[(size_t)b * (4096 * 512) + (size_t)(n0 + nn) * 512 + c0 + tx] =
        f2bf(tile[tx][nn]);
  }
}

// ---------------- conv1x1 GEMMs: Y = W X^T + bias ------------------------
// trans=1 (Q,K): operand-swapped -> rows=n (A=X), cols=o (B=W); store
// out[n][o] with o in the lane dim. trans=0 (V): rows=o, cols=n.
struct ConvArgs {
  const unsigned short* W[12];
  const unsigned short* X[12];
  const float* bias[12];
  unsigned short* out[12];
  int trans[12];
};
__global__ __launch_bounds__(256) void k_conv(ConvArgs a) {
  __shared__ unsigned short sh[16384];
  int z = blockIdx.z;
  int trans = a.trans[z];
  int rowbase = (trans ? blockIdx.x : blockIdx.y) << 7;
  int colbase = (trans ? blockIdx.y : blockIdx.x) << 7;
  const unsigned short* Ag = trans ? a.X[z] : a.W[z];
  const unsigned short* Bg = trans ? a.W[z] : a.X[z];
  f32x4 acc[4][4];
#pragma unroll
  for (int i = 0; i < 4; ++i)
#pragma unroll
    for (int j = 0; j < 4; ++j) acc[i][j] = (f32x4){0.f, 0.f, 0.f, 0.f};
  gemm_core<2>(Ag, Bg, 512, 512, 512, rowbase, colbase, acc, sh, sh + 8192);

  const int tid = threadIdx.x, w = tid >> 6, lane = tid & 63;
  const int quad = lane >> 4, l16 = lane & 15;
  const int wm = (w >> 1) << 6, wn = (w & 1) << 6;
  const float* bias = a.bias[z];
  unsigned short* out = a.out[z];
  if (trans) {
    float bo[4];
#pragma unroll
    for (int j = 0; j < 4; ++j) bo[j] = bias[colbase + wn + (j << 4) + l16];
#pragma unroll
    for (int i = 0; i < 4; ++i) {
      int n0 = rowbase + wm + (i << 4) + (quad << 2);
#pragma unroll
      for (int j = 0; j < 4; ++j) {
        int o = colbase + wn + (j << 4) + l16;
        out[(size_t)(n0 + 0) * 512 + o] = f2bf(acc[i][j].x + bo[j]);
        out[(size_t)(n0 + 1) * 512 + o] = f2bf(acc[i][j].y + bo[j]);
        out[(size_t)(n0 + 2) * 512 + o] = f2bf(acc[i][j].z + bo[j]);
        out[(size_t)(n0 + 3) * 512 + o] = f2bf(acc[i][j].w + bo[j]);
      }
    }
  } else {
#pragma unroll
    for (int i = 0; i < 4; ++i) {
      int o0 = rowbase + wm + (i << 4) + (quad << 2);
      float b0 = bias[o0], b1 = bias[o0 + 1], b2 = bias[o0 + 2], b3 = bias[o0 + 3];
#pragma unroll
      for (int j = 0; j < 4; ++j) {
        int n = colbase + wn + (j << 4) + l16;
        out[(size_t)(o0 + 0) * 4096 + n] = f2bf(acc[i][j].x + b0);
        out[(size_t)(o0 + 1) * 4096 + n] = f2bf(acc[i][j].y + b1);
        out[(size_t)(o0 + 2) * 4096 + n] = f2bf(acc[i][j].z + b2);
        out[(size_t)(o0 + 3) * 4096 + n] = f2bf(acc[i][j].w + b3);
      }
    }
  }
}

// ---------------- Et[n][m] = exp(Qt Kt^T), fused partial sum S[m] --------
// OPERAND-SWAPPED: A=Qt (rows=n), B=Kt (cols=m) -> m is the lane dim.
struct QKArgs {
  const unsigned short* Q[4]; const unsigned short* K[4]; unsigned short* T[4];
  float* pz;  // [4 z][32 nblk][4096 m] partial sums
};
__global__ __launch_bounds__(256) void k_qk(QKArgs a) {
  __shared__ unsigned short sh[16384];
  int z = blockIdx.z;
  int nbase = blockIdx.y << 7;  // rows = n
  int mbase = blockIdx.x << 7;  // cols = m
  f32x4 acc[4][4];
#pragma unroll
  for (int i = 0; i < 4; ++i)
#pragma unroll
    for (int j = 0; j < 4; ++j) acc[i][j] = (f32x4){0.f, 0.f, 0.f, 0.f};
  gemm_core<2>(a.Q[z], a.K[z], 512, 512, 512, nbase, mbase, acc, sh, sh + 8192);

  const int tid = threadIdx.x, w = tid >> 6, lane = tid & 63;
  const int quad = lane >> 4, l16 = lane & 15;
  const int wm = (w >> 1) << 6, wn = (w & 1) << 6;
  unsigned short* T = a.T[z];
  float sjv[4] = {0.f, 0.f, 0.f, 0.f};
#pragma unroll
  for (int i = 0; i < 4; ++i) {
    int n0 = nbase + wm + (i << 4) + (quad << 2);
#pragma unroll
    for (int j = 0; j < 4; ++j) {
      int m = mbase + wn + (j << 4) + l16;
      float e0 = __expf(acc[i][j].x);
      float e1 = __expf(acc[i][j].y);
      float e2 = __expf(acc[i][j].z);
      float e3 = __expf(acc[i][j].w);
      T[(size_t)(n0 + 0) * 4096 + m] = f2bf(e0);
      T[(size_t)(n0 + 1) * 4096 + m] = f2bf(e1);
      T[(size_t)(n0 + 2) * 4096 + m] = f2bf(e2);
      T[(size_t)(n0 + 3) * 4096 + m] = f2bf(e3);
      sjv[j] += e0 + e1 + e2 + e3;
    }
  }
  float* red = (float*)sh;  // [4 waves][64 m-local]
#pragma unroll
  for (int j = 0; j < 4; ++j) {
    float s = sjv[j];
    s += __shfl_xor(s, 16, 64);
    s += __shfl_xor(s, 32, 64);
    if (quad == 0) red[(w << 6) + (j << 4) + l16] = s;
  }
  __syncthreads();
  if (tid < 128) {
    int h = tid >> 6, t = tid & 63;
    float S = red[(h << 6) + t] + red[((h + 2) << 6) + t];
    int m = mbase + (h << 6) + t;
    a.pz[((z << 5) + blockIdx.y) * 4096 + m] = S;
  }
}

// ---------------- merge 32 partials -> c[m] = 1/S ------------------------
__global__ __launch_bounds__(256) void k_stats2(const float* __restrict__ pz,
                                                float* __restrict__ c) {
  int m = (blockIdx.x << 8) + threadIdx.x;
  int z = blockIdx.y;
  float S = 0.f;
#pragma unroll
  for (int k = 0; k < 32; ++k) S += pz[((z << 5) + k) * 4096 + m];
  c[z * 4096 + m] = 1.f / S;
}

// ---------------- V'[c][m] = V[c][m] * c[m] (in place) -------------------
struct VSArgs { unsigned short* V[4]; const float* c; };
__global__ __launch_bounds__(256) void k_vscale(VSArgs a) {
  int z = blockIdx.y;
  int t = blockIdx.x * 256 + threadIdx.x;
  int m0 = (t & 511) << 3;
  int row = t >> 9;
  unsigned short* p = a.V[z] + (size_t)row * 4096 + m0;
  const float* cz = a.c + z * 4096 + m0;
  int4 raw = *(const int4*)p;
  unsigned short* u = (unsigned short*)&raw;
#pragma unroll
  for (int j = 0; j < 8; ++j) u[j] = f2bf(bf2f(u[j]) * cz[j]);
  *(int4*)p = raw;
}

// ---------------- O partials: split-K pure bf16 GEMM ---------------------
struct PVArgs {
  const unsigned short* V[4];
  const unsigned short* P[4];  // Et[n][m]
  float* part[8];              // [kc*4 + z] -> f32 [512][4096]
};
__global__ __launch_bounds__(256) void k_pv(PVArgs a) {
  __shared__ unsigned short sh[16384];  // NSUB=2: 32 KB -> 4 blocks/CU
  int zk = blockIdx.z;
  int z = zk & 3, kc = zk >> 2;
  int rowbase = blockIdx.y << 7;  // c
  int colbase = blockIdx.x << 7;  // n
  f32x4 acc[4][4];
#pragma unroll
  for (int i = 0; i < 4; ++i)
#pragma unroll
    for (int j = 0; j < 4; ++j) acc[i][j] = (f32x4){0.f, 0.f, 0.f, 0.f};
  gemm_core<2>(a.V[z] + (kc << 11), a.P[z] + (kc << 11), 2048, 4096, 4096,
               rowbase, colbase, acc, sh, sh + 8192);

  const int tid = threadIdx.x, w = tid >> 6, lane = tid & 63;
  const int quad = lane >> 4, l16 = lane & 15;
  const int wm = (w >> 1) << 6, wn = (w & 1) << 6;
  float* O = a.part[zk];
#pragma unroll
  for (int i = 0; i < 4; ++i) {
    int c0 = rowbase + wm + (i << 4) + (quad << 2);
#pragma unroll
    for (int j = 0; j < 4; ++j) {
      int n = colbase + wn + (j << 4) + l16;
      O[(size_t)(c0 + 0) * 4096 + n] = acc[i][j].x;
      O[(size_t)(c0 + 1) * 4096 + n] = acc[i][j].y;
      O[(size_t)(c0 + 2) * 4096 + n] = acc[i][j].z;
      O[(size_t)(c0 + 3) * 4096 + n] = acc[i][j].w;
    }
  }
}

// ---------------- out = relu(gamma*(p0+p1) + resid) ----------------------
struct RedArgs {
  const float* p1[4];
  const float* resid[4];
  const float* gamma[4];
  float* out[4];  // holds p0, overwritten in place
};
__global__ __launch_bounds__(256) void k_red(RedArgs a) {
  int z = blockIdx.y;
  size_t i = ((size_t)blockIdx.x * 256 + threadIdx.x) << 2;  // float4 granular
  float4 v0 = *(const float4*)(a.out[z] + i);
  float4 v1 = *(const float4*)(a.p1[z] + i);
  float4 r  = *(const float4*)(a.resid[z] + i);
  float g = a.gamma[z][0];
  float4 o;
  o.x = fmaxf(g * (v0.x + v1.x) + r.x, 0.f);
  o.y = fmaxf(g * (v0.y + v1.y) + r.y, 0.f);
  o.z = fmaxf(g * (v0.z + v1.z) + r.z, 0.f);
  o.w = fmaxf(g * (v0.w + v1.w) + r.w, 0.f);
  *(float4*)(a.out[z] + i) = o;
}

// ---------------------------------------------------------------------------
extern "C" void kernel_launch(void* const* d_in, const int* in_sizes, int n_in,
                              void* d_out, int out_size, void* d_ws, size_t ws_size,
                              hipStream_t stream) {
  char* ws = (char*)d_ws;
  unsigned short* wb  = (unsigned short*)(ws);              //  6 x 512x512 bf16
  unsigned short* xt  = (unsigned short*)(ws + 3145728);    //  4 x [2][4096][512]
  unsigned short* qkv = (unsigned short*)(ws + 36700160);   // 12 x [4096x512]
  unsigned short* tt  = (unsigned short*)(ws + 87031808);   //  4 x [4096x4096]
  float* pz  = (float*)(ws + 3145728);                      // overlaps dead xt
  float* cb  = (float*)(ws + 3145728 + 2097152);

  // 1. weights -> bf16
  WArgs wa;
  for (int i = 0; i < 6; ++i) {
    wa.src[i] = (const float*)d_in[4 + 2 * i];
    wa.dst[i] = wb + (size_t)i * 262144;
  }
  k_cvtw<<<dim3(1024, 6), 256, 0, stream>>>(wa);

  // 2. feature maps -> transposed bf16 Xt[b][n][c]
  TArgs ta;
  for (int ai = 0; ai < 4; ++ai) {
    ta.src[ai] = (const float*)d_in[ai];
    ta.dst[ai] = xt + (size_t)ai * 4194304;
  }
  k_tcvt<<<dim3(128, 32, 4), 256, 0, stream>>>(ta);

  // 3. six convs x two batches (q_rd, k_rd, v_rd, q_dr, k_dr, v_dr)
  const int srcArr[6] = {2, 0, 3, 3, 1, 1};
  const int trans[6] = {1, 1, 0, 1, 1, 0};
  ConvArgs ca;
  for (int ci = 0; ci < 6; ++ci)
    for (int b = 0; b < 2; ++b) {
      int zz = ci * 2 + b;
      ca.W[zz] = wb + (size_t)ci * 262144;
      ca.X[zz] = xt + (size_t)srcArr[ci] * 4194304 + (size_t)b * 2097152;
      ca.bias[zz] = (const float*)d_in[5 + 2 * ci];
      ca.out[zz] = qkv + (size_t)zz * 2097152;
      ca.trans[zz] = trans[ci];
    }
  k_conv<<<dim3(32, 4, 12), 256, 0, stream>>>(ca);

  // 4. Et[n][m] = exp(Qt Kt^T) + fused partial sums (operand-swapped)
  QKArgs qa;
  for (int path = 0; path < 2; ++path)
    for (int b = 0; b < 2; ++b) {
      int zz = path * 2 + b;
      qa.Q[zz] = qkv + (size_t)((path * 3 + 0) * 2 + b) * 2097152;  // Qt (rows=n)
      qa.K[zz] = qkv + (size_t)((path * 3 + 1) * 2 + b) * 2097152;  // Kt (cols=m)
      qa.T[zz] = tt + (size_t)zz * 16777216;
    }
  qa.pz = pz;
  k_qk<<<dim3(32, 32, 4), 256, 0, stream>>>(qa);

  // 5. merge partials -> c[m] = 1/S
  k_stats2<<<dim3(16, 4), 256, 0, stream>>>(pz, cb);

  // 6. V' = V * c[m]
  VSArgs va;
  for (int path = 0; path < 2; ++path)
    for (int b = 0; b < 2; ++b)
      va.V[path * 2 + b] = qkv + (size_t)((path * 3 + 2) * 2 + b) * 2097152;
  va.c = cb;
  k_vscale<<<dim3(1024, 4), 256, 0, stream>>>(va);

  // 7. split-K GEMM: kc=0 partial -> d_out; kc=1 -> dead Q/K qkv slots
  //    (slots 0-1, 2-3, 6-7, 8-9 hold the four 8 MB f32 partials; V' slots
  //     4,5,10,11 remain live.)
  PVArgs pa;
  float* p1base[4] = {
      (float*)(qkv + (size_t)0 * 2097152),
      (float*)(qkv + (size_t)2 * 2097152),
      (float*)(qkv + (size_t)6 * 2097152),
      (float*)(qkv + (size_t)8 * 2097152)};
  for (int path = 0; path < 2; ++path)
    for (int b = 0; b < 2; ++b) {
      int zz = path * 2 + b;
      pa.V[zz] = qkv + (size_t)((path * 3 + 2) * 2 + b) * 2097152;
      pa.P[zz] = tt + (size_t)zz * 16777216;
      pa.part[zz] = (float*)d_out + (size_t)zz * 2097152;  // kc=0
      pa.part[4 + zz] = p1base[zz];                        // kc=1
    }
  k_pv<<<dim3(32, 4, 8), 256, 0, stream>>>(pa);

  // 8. reduce + epilogue
  RedArgs ra;
  const float* resid_src[2] = {(const float*)d_in[2], (const float*)d_in[3]};
  const float* gsrc[2] = {(const float*)d_in[16], (const float*)d_in[17]};
  for (int path = 0; path < 2; ++path)
    for (int b = 0; b < 2; ++b) {
      int zz = path * 2 + b;
      ra.p1[zz] = p1base[zz];
      ra.resid[zz] = resid_src[path] + (size_t)b * 2097152;
      ra.gamma[zz] = gsrc[path];
      ra.out[zz] = (float*)d_out + (size_t)zz * 2097152;
    }
  k_red<<<dim3(2048, 4), 256, 0, stream>>>(ra);
}

// Round 9
// 374.535 us; speedup vs baseline: 1.1028x; 1.1028x over previous
//
#include <hip/hip_runtime.h>
#include <stdint.h>

// ---------------------------------------------------------------------------
// FeatureMapTransformer: dual cross-attention (rd / dr paths), B=2, C=512,
// H=W=64 -> N=M=4096.
//   Qt[n][c], Kt[m][c] (transposed conv outs), V[c][m]        (bf16)
//   Et[n][m] = bf16(exp(sum_c Kt[m][c] Qt[n][c]))             (k_qk)
//   partial S[m] = sum_n exp(T) fused into k_qk -> c[m] = 1/S (k_stats2)
//   V'[c][m] = V[c][m] * c[m]                                 (k_vscale)
//   O[c][n]  = sum_m V'[c][m] E[n][m]  (pure bf16 GEMM)       (k_pv, NSUB=4)
//   out = relu(gamma*O + resid)  (fused k_pv epilogue)
// Staging: global_load_lds width-16 async DMA, NSUB 32-k sub-tiles per
// barrier pair; XOR chunk swizzle on the GLOBAL address side -> fragment
// ds_read_b128 at free 2-way aliasing (0 conflicts, verified r5/r7).
// Round-8 split-K REVERTED: 2x blocks/CU left k_pv duration unchanged
// (110 vs 112) -- the stall is the synchronized barrier vmcnt drain, not
// block-level occupancy -- and f32 partials + k_red added ~33 us.
// Round-9: vectorized k_tcvt (float4 reads, int4 bf16x8 writes via f32 LDS
// tile) and k_cvtw (int4) -- the old scalar-b16-store transpose ran well
// under HBM write peak on 402 MB of traffic.
// ---------------------------------------------------------------------------

typedef __attribute__((ext_vector_type(8))) __bf16 bf16x8;
typedef __attribute__((ext_vector_type(4))) float f32x4;

__device__ __forceinline__ unsigned short f2bf(float f) {
  union { float f; unsigned u; } v; v.f = f;
  unsigned r = v.u + 0x7FFFu + ((v.u >> 16) & 1u);
  return (unsigned short)(r >> 16);
}
__device__ __forceinline__ float bf2f(unsigned short b) {
  union { unsigned u; float f; } v; v.u = ((unsigned)b) << 16;
  return v.f;
}

__device__ __forceinline__ void async_copy16(const unsigned short* g,
                                             unsigned short* l) {
  __builtin_amdgcn_global_load_lds(
      (const __attribute__((address_space(1))) unsigned int*)g,
      (__attribute__((address_space(3))) unsigned int*)l, 16, 0, 0);
}

// C[128x128 at (rowbase,colbase)] += A[row][k] * B[col][k]^T, K-contig A/B.
// Al/Bl: NSUB sub-tiles of 128x32 (4096 shorts each). 16B chunk c of row r
// lives at slot c^((r>>1)&3).
template <int NSUB>
__device__ __forceinline__ void gemm_core(
    const unsigned short* __restrict__ Ag, const unsigned short* __restrict__ Bg,
    int K, int lda, int ldb, int rowbase, int colbase,
    f32x4 (&acc)[4][4], unsigned short* Al, unsigned short* Bl) {
  const int tid = threadIdx.x;
  const int w = tid >> 6, lane = tid & 63;
  const int quad = lane >> 4, l16 = lane & 15;
  const int wm = (w >> 1) << 6, wn = (w & 1) << 6;
  const int rbase = (w << 5) + (lane >> 2);

  for (int k0 = 0; k0 < K; k0 += 32 * NSUB) {
#pragma unroll
    for (int half = 0; half < NSUB; ++half) {
      int kh = k0 + (half << 5);
      unsigned short* Ah = Al + (half << 12);
      unsigned short* Bh = Bl + (half << 12);
#pragma unroll
      for (int i = 0; i < 2; ++i) {
        int rloc = rbase + (i << 4);
        int cg = (lane & 3) ^ ((rloc >> 1) & 3);
        int koff = kh + (cg << 3);
        int ldsoff = ((w << 5) + (i << 4)) << 5;
        async_copy16(Ag + (size_t)(rowbase + rloc) * lda + koff, Ah + ldsoff);
        async_copy16(Bg + (size_t)(colbase + rloc) * ldb + koff, Bh + ldsoff);
      }
    }
    __syncthreads();
#pragma unroll
    for (int half = 0; half < NSUB; ++half) {
      unsigned short* Ah = Al + (half << 12);
      unsigned short* Bh = Bl + (half << 12);
      bf16x8 af[4], bfr[4];
#pragma unroll
      for (int i = 0; i < 4; ++i) {
        int r = wm + (i << 4) + l16;
        af[i] = *(const bf16x8*)(Ah + (r << 5) + ((quad ^ ((r >> 1) & 3)) << 3));
      }
#pragma unroll
      for (int j = 0; j < 4; ++j) {
        int r = wn + (j << 4) + l16;
        bfr[j] = *(const bf16x8*)(Bh + (r << 5) + ((quad ^ ((r >> 1) & 3)) << 3));
      }
#pragma unroll
      for (int i = 0; i < 4; ++i)
#pragma unroll
        for (int j = 0; j < 4; ++j)
          acc[i][j] = __builtin_amdgcn_mfma_f32_16x16x32_bf16(af[i], bfr[j], acc[i][j], 0, 0, 0);
    }
    __syncthreads();
  }
}

// ---------------- weight fp32 -> bf16 (vectorized) -----------------------
struct WArgs { const float* src[6]; unsigned short* dst[6]; };
__global__ __launch_bounds__(256) void k_cvtw(WArgs a) {
  int z = blockIdx.y;
  int i = (blockIdx.x * 256 + threadIdx.x) << 3;
  const float* s = a.src[z] + i;
  float4 v0 = *(const float4*)s;
  float4 v1 = *(const float4*)(s + 4);
  unsigned short pk[8] = {f2bf(v0.x), f2bf(v0.y), f2bf(v0.z), f2bf(v0.w),
                          f2bf(v1.x), f2bf(v1.y), f2bf(v1.z), f2bf(v1.w)};
  *(int4*)(a.dst[z] + i) = *(int4*)pk;
}

// ---------------- transpose+convert: x[b][c][n] f32 -> Xt[b][n][c] bf16 --
// 64n x 32c tile: float4 coalesced reads -> f32 LDS (stride 68: 16B-aligned
// float4 stores) -> 8 scalar LDS reads (4-way bank = 1.58x, acceptable) ->
// packed int4 bf16x8 stores (wave writes 1 KB in optimal 32B sectors).
struct TArgs { const float* src[4]; unsigned short* dst[4]; };
__global__ __launch_bounds__(256) void k_tcvt(TArgs a) {
  __shared__ float tile[32][68];
  int z = blockIdx.z;  // array*2 + b
  const float* src = a.src[z >> 1] + (size_t)(z & 1) * (512 * 4096);
  unsigned short* dst = a.dst[z >> 1] + (size_t)(z & 1) * (4096 * 512);
  int n0 = blockIdx.x << 6;  // 64 n
  int c0 = blockIdx.y << 5;  // 32 c
  int tid = threadIdx.x;
  int q = tid & 15, r0 = tid >> 4;  // 16 lanes/row, 16 c-rows/pass
#pragma unroll
  for (int pass = 0; pass < 2; ++pass) {
    int r = r0 + (pass << 4);
    *(float4*)&tile[r][q << 2] =
        *(const float4*)(src + (size_t)(c0 + r) * 4096 + n0 + (q << 2));
  }
  __syncthreads();
  int j = tid >> 2, c8 = (tid & 3) << 3;  // n row j, 8 c's per thread
  unsigned short pk[8];
#pragma unroll
  for (int k = 0; k < 8; ++k) pk[k] = f2bf(tile[c8 + k][j]);
  *(int4*)(dst + (size_t)(n0 + j) * 512 + c0 + c8) = *(int4*)pk;
}

// ---------------- conv1x1 GEMMs: Y = W X^T + bias ------------------------
// trans=1 (Q,K): operand-swapped -> rows=n (A=X), cols=o (B=W); store
// out[n][o] with o in the lane dim. trans=0 (V): rows=o, cols=n.
struct ConvArgs {
  const unsigned short* W[12];
  const unsigned short* X[12];
  const float* bias[12];
  unsigned short* out[12];
  int trans[12];
};
__global__ __launch_bounds__(256) void k_conv(ConvArgs a) {
  __shared__ unsigned short sh[16384];
  int z = blockIdx.z;
  int trans = a.trans[z];
  int rowbase = (trans ? blockIdx.x : blockIdx.y) << 7;
  int colbase = (trans ? blockIdx.y : blockIdx.x) << 7;
  const unsigned short* Ag = trans ? a.X[z] : a.W[z];
  const unsigned short* Bg = trans ? a.W[z] : a.X[z];
  f32x4 acc[4][4];
#pragma unroll
  for (int i = 0; i < 4; ++i)
#pragma unroll
    for (int j = 0; j < 4; ++j) acc[i][j] = (f32x4){0.f, 0.f, 0.f, 0.f};
  gemm_core<2>(Ag, Bg, 512, 512, 512, rowbase, colbase, acc, sh, sh + 8192);

  const int tid = threadIdx.x, w = tid >> 6, lane = tid & 63;
  const int quad = lane >> 4, l16 = lane & 15;
  const int wm = (w >> 1) << 6, wn = (w & 1) << 6;
  const float* bias = a.bias[z];
  unsigned short* out = a.out[z];
  if (trans) {
    float bo[4];
#pragma unroll
    for (int j = 0; j < 4; ++j) bo[j] = bias[colbase + wn + (j << 4) + l16];
#pragma unroll
    for (int i = 0; i < 4; ++i) {
      int n0 = rowbase + wm + (i << 4) + (quad << 2);
#pragma unroll
      for (int j = 0; j < 4; ++j) {
        int o = colbase + wn + (j << 4) + l16;
        out[(size_t)(n0 + 0) * 512 + o] = f2bf(acc[i][j].x + bo[j]);
        out[(size_t)(n0 + 1) * 512 + o] = f2bf(acc[i][j].y + bo[j]);
        out[(size_t)(n0 + 2) * 512 + o] = f2bf(acc[i][j].z + bo[j]);
        out[(size_t)(n0 + 3) * 512 + o] = f2bf(acc[i][j].w + bo[j]);
      }
    }
  } else {
#pragma unroll
    for (int i = 0; i < 4; ++i) {
      int o0 = rowbase + wm + (i << 4) + (quad << 2);
      float b0 = bias[o0], b1 = bias[o0 + 1], b2 = bias[o0 + 2], b3 = bias[o0 + 3];
#pragma unroll
      for (int j = 0; j < 4; ++j) {
        int n = colbase + wn + (j << 4) + l16;
        out[(size_t)(o0 + 0) * 4096 + n] = f2bf(acc[i][j].x + b0);
        out[(size_t)(o0 + 1) * 4096 + n] = f2bf(acc[i][j].y + b1);
        out[(size_t)(o0 + 2) * 4096 + n] = f2bf(acc[i][j].z + b2);
        out[(size_t)(o0 + 3) * 4096 + n] = f2bf(acc[i][j].w + b3);
      }
    }
  }
}

// ---------------- Et[n][m] = exp(Qt Kt^T), fused partial sum S[m] --------
// OPERAND-SWAPPED: A=Qt (rows=n), B=Kt (cols=m) -> m is the lane dim.
struct QKArgs {
  const unsigned short* Q[4]; const unsigned short* K[4]; unsigned short* T[4];
  float* pz;  // [4 z][32 nblk][4096 m] partial sums
};
__global__ __launch_bounds__(256) void k_qk(QKArgs a) {
  __shared__ unsigned short sh[16384];
  int z = blockIdx.z;
  int nbase = blockIdx.y << 7;  // rows = n
  int mbase = blockIdx.x << 7;  // cols = m
  f32x4 acc[4][4];
#pragma unroll
  for (int i = 0; i < 4; ++i)
#pragma unroll
    for (int j = 0; j < 4; ++j) acc[i][j] = (f32x4){0.f, 0.f, 0.f, 0.f};
  gemm_core<2>(a.Q[z], a.K[z], 512, 512, 512, nbase, mbase, acc, sh, sh + 8192);

  const int tid = threadIdx.x, w = tid >> 6, lane = tid & 63;
  const int quad = lane >> 4, l16 = lane & 15;
  const int wm = (w >> 1) << 6, wn = (w & 1) << 6;
  unsigned short* T = a.T[z];
  float sjv[4] = {0.f, 0.f, 0.f, 0.f};
#pragma unroll
  for (int i = 0; i < 4; ++i) {
    int n0 = nbase + wm + (i << 4) + (quad << 2);
#pragma unroll
    for (int j = 0; j < 4; ++j) {
      int m = mbase + wn + (j << 4) + l16;
      float e0 = __expf(acc[i][j].x);
      float e1 = __expf(acc[i][j].y);
      float e2 = __expf(acc[i][j].z);
      float e3 = __expf(acc[i][j].w);
      T[(size_t)(n0 + 0) * 4096 + m] = f2bf(e0);
      T[(size_t)(n0 + 1) * 4096 + m] = f2bf(e1);
      T[(size_t)(n0 + 2) * 4096 + m] = f2bf(e2);
      T[(size_t)(n0 + 3) * 4096 + m] = f2bf(e3);
      sjv[j] += e0 + e1 + e2 + e3;
    }
  }
  float* red = (float*)sh;  // [4 waves][64 m-local]
#pragma unroll
  for (int j = 0; j < 4; ++j) {
    float s = sjv[j];
    s += __shfl_xor(s, 16, 64);
    s += __shfl_xor(s, 32, 64);
    if (quad == 0) red[(w << 6) + (j << 4) + l16] = s;
  }
  __syncthreads();
  if (tid < 128) {
    int h = tid >> 6, t = tid & 63;
    float S = red[(h << 6) + t] + red[((h + 2) << 6) + t];
    int m = mbase + (h << 6) + t;
    a.pz[((z << 5) + blockIdx.y) * 4096 + m] = S;
  }
}

// ---------------- merge 32 partials -> c[m] = 1/S ------------------------
__global__ __launch_bounds__(256) void k_stats2(const float* __restrict__ pz,
                                                float* __restrict__ c) {
  int m = (blockIdx.x << 8) + threadIdx.x;
  int z = blockIdx.y;
  float S = 0.f;
#pragma unroll
  for (int k = 0; k < 32; ++k) S += pz[((z << 5) + k) * 4096 + m];
  c[z * 4096 + m] = 1.f / S;
}

// ---------------- V'[c][m] = V[c][m] * c[m] (in place) -------------------
struct VSArgs { unsigned short* V[4]; const float* c; };
__global__ __launch_bounds__(256) void k_vscale(VSArgs a) {
  int z = blockIdx.y;
  int t = blockIdx.x * 256 + threadIdx.x;
  int m0 = (t & 511) << 3;
  int row = t >> 9;
  unsigned short* p = a.V[z] + (size_t)row * 4096 + m0;
  const float* cz = a.c + z * 4096 + m0;
  int4 raw = *(const int4*)p;
  unsigned short* u = (unsigned short*)&raw;
#pragma unroll
  for (int j = 0; j < 8; ++j) u[j] = f2bf(bf2f(u[j]) * cz[j]);
  *(int4*)p = raw;
}

// ---------------- O = V' E, epilogue relu(gamma*O + resid) ---------------
struct PVArgs {
  const unsigned short* V[4];
  const unsigned short* P[4];  // Et[n][m]
  const float* resid[4];
  const float* gamma[4];
  float* out[4];
};
__global__ __launch_bounds__(256) void k_pv(PVArgs a) {
  __shared__ unsigned short sh[32768];  // BK=128: 4 sub-tiles each side, 64 KB
  int z = blockIdx.z;
  int rowbase = blockIdx.y << 7;  // c
  int colbase = blockIdx.x << 7;  // n
  f32x4 acc[4][4];
#pragma unroll
  for (int i = 0; i < 4; ++i)
#pragma unroll
    for (int j = 0; j < 4; ++j) acc[i][j] = (f32x4){0.f, 0.f, 0.f, 0.f};
  gemm_core<4>(a.V[z], a.P[z], 4096, 4096, 4096, rowbase, colbase, acc, sh, sh + 16384);

  const int tid = threadIdx.x, w = tid >> 6, lane = tid & 63;
  const int quad = lane >> 4, l16 = lane & 15;
  const int wm = (w >> 1) << 6, wn = (w & 1) << 6;
  float g = a.gamma[z][0];
  const float* R = a.resid[z];
  float* O = a.out[z];
#pragma unroll
  for (int i = 0; i < 4; ++i) {
    int c0 = rowbase + wm + (i << 4) + (quad << 2);
#pragma unroll
    for (int j = 0; j < 4; ++j) {
      int n = colbase + wn + (j << 4) + l16;
      O[(size_t)(c0 + 0) * 4096 + n] = fmaxf(g * acc[i][j].x + R[(size_t)(c0 + 0) * 4096 + n], 0.f);
      O[(size_t)(c0 + 1) * 4096 + n] = fmaxf(g * acc[i][j].y + R[(size_t)(c0 + 1) * 4096 + n], 0.f);
      O[(size_t)(c0 + 2) * 4096 + n] = fmaxf(g * acc[i][j].z + R[(size_t)(c0 + 2) * 4096 + n], 0.f);
      O[(size_t)(c0 + 3) * 4096 + n] = fmaxf(g * acc[i][j].w + R[(size_t)(c0 + 3) * 4096 + n], 0.f);
    }
  }
}

// ---------------------------------------------------------------------------
extern "C" void kernel_launch(void* const* d_in, const int* in_sizes, int n_in,
                              void* d_out, int out_size, void* d_ws, size_t ws_size,
                              hipStream_t stream) {
  char* ws = (char*)d_ws;
  unsigned short* wb  = (unsigned short*)(ws);              //  6 x 512x512 bf16
  unsigned short* xt  = (unsigned short*)(ws + 3145728);    //  4 x [2][4096][512]
  unsigned short* qkv = (unsigned short*)(ws + 36700160);   // 12 x [4096x512]
  unsigned short* tt  = (unsigned short*)(ws + 87031808);   //  4 x [4096x4096]
  float* pz  = (float*)(ws + 3145728);                      // overlaps dead xt
  float* cb  = (float*)(ws + 3145728 + 2097152);

  // 1. weights -> bf16
  WArgs wa;
  for (int i = 0; i < 6; ++i) {
    wa.src[i] = (const float*)d_in[4 + 2 * i];
    wa.dst[i] = wb + (size_t)i * 262144;
  }
  k_cvtw<<<dim3(128, 6), 256, 0, stream>>>(wa);

  // 2. feature maps -> transposed bf16 Xt[b][n][c]
  TArgs ta;
  for (int ai = 0; ai < 4; ++ai) {
    ta.src[ai] = (const float*)d_in[ai];
    ta.dst[ai] = xt + (size_t)ai * 4194304;
  }
  k_tcvt<<<dim3(64, 16, 8), 256, 0, stream>>>(ta);

  // 3. six convs x two batches (q_rd, k_rd, v_rd, q_dr, k_dr, v_dr)
  const int srcArr[6] = {2, 0, 3, 3, 1, 1};
  const int trans[6] = {1, 1, 0, 1, 1, 0};
  ConvArgs ca;
  for (int ci = 0; ci < 6; ++ci)
    for (int b = 0; b < 2; ++b) {
      int zz = ci * 2 + b;
      ca.W[zz] = wb + (size_t)ci * 262144;
      ca.X[zz] = xt + (size_t)srcArr[ci] * 4194304 + (size_t)b * 2097152;
      ca.bias[zz] = (const float*)d_in[5 + 2 * ci];
      ca.out[zz] = qkv + (size_t)zz * 2097152;
      ca.trans[zz] = trans[ci];
    }
  k_conv<<<dim3(32, 4, 12), 256, 0, stream>>>(ca);

  // 4. Et[n][m] = exp(Qt Kt^T) + fused partial sums (operand-swapped)
  QKArgs qa;
  for (int path = 0; path < 2; ++path)
    for (int b = 0; b < 2; ++b) {
      int zz = path * 2 + b;
      qa.Q[zz] = qkv + (size_t)((path * 3 + 0) * 2 + b) * 2097152;  // Qt (rows=n)
      qa.K[zz] = qkv + (size_t)((path * 3 + 1) * 2 + b) * 2097152;  // Kt (cols=m)
      qa.T[zz] = tt + (size_t)zz * 16777216;
    }
  qa.pz = pz;
  k_qk<<<dim3(32, 32, 4), 256, 0, stream>>>(qa);

  // 5. merge partials -> c[m] = 1/S
  k_stats2<<<dim3(16, 4), 256, 0, stream>>>(pz, cb);

  // 6. V' = V * c[m]
  VSArgs va;
  for (int path = 0; path < 2; ++path)
    for (int b = 0; b < 2; ++b)
      va.V[path * 2 + b] = qkv + (size_t)((path * 3 + 2) * 2 + b) * 2097152;
  va.c = cb;
  k_vscale<<<dim3(1024, 4), 256, 0, stream>>>(va);

  // 7. O = V' E + fused epilogue (pure bf16 GEMM, BK=128)
  PVArgs pa;
  const float* resid_src[2] = {(const float*)d_in[2], (const float*)d_in[3]};
  const float* gsrc[2] = {(const float*)d_in[16], (const float*)d_in[17]};
  for (int path = 0; path < 2; ++path)
    for (int b = 0; b < 2; ++b) {
      int zz = path * 2 + b;
      pa.V[zz] = qkv + (size_t)((path * 3 + 2) * 2 + b) * 2097152;
      pa.P[zz] = tt + (size_t)zz * 16777216;
      pa.resid[zz] = resid_src[path] + (size_t)b * 2097152;
      pa.gamma[zz] = gsrc[path];
      pa.out[zz] = (float*)d_out + (size_t)zz * 2097152;
    }
  k_pv<<<dim3(32, 4, 4), 256, 0, stream>>>(pa);
}